// Round 1
// baseline (1001.589 us; speedup 1.0000x reference)
//
#include <hip/hip_runtime.h>

#define HID    64
#define TSTEPS 256
#define BATCH  2048

// tanh(x) = 1 - 2/(exp2(2*log2(e)*x) + 1); exact at saturation (inf -> 1, 0 -> -1)
__device__ __forceinline__ float fast_tanh(float x) {
    float e = __builtin_amdgcn_exp2f(x * 2.8853900817779268f);
    float r = __builtin_amdgcn_rcpf(e + 1.0f);
    return fmaf(-2.0f, r, 1.0f);
}

// broadcast lane `l`'s value to all lanes via v_readlane (SGPR result -> fmac src0)
__device__ __forceinline__ float bcast_lane(float v, int l) {
    return __int_as_float(__builtin_amdgcn_readlane(__float_as_int(v), l));
}

__global__ __launch_bounds__(256, 2) void hnn_rk4_kernel(
        const float* __restrict__ tarr,
        const float* __restrict__ x0,
        const float* __restrict__ W1,
        const float* __restrict__ b1,
        const float* __restrict__ W2,
        const float* __restrict__ b2,
        const float* __restrict__ W3,
        float* __restrict__ out)
{
    const int lane = threadIdx.x & 63;
    const int wid  = threadIdx.x >> 6;
    const int b    = blockIdx.x * (blockDim.x >> 6) + wid;   // batch element, one wave each

    const float dt  = tarr[1] - tarr[0];
    const float hdt = 0.5f * dt;
    const float sdt = dt * (1.0f / 6.0f);

    // lane i owns hidden unit i
    const int i = lane;
    const float w1a = W1[2 * i + 0];   // W1[i,0] (q column)
    const float w1b = W1[2 * i + 1];   // W1[i,1] (p column)
    const float b1i = b1[i];
    const float b2i = b2[i];
    const float w3i = W3[i];

    // W2 row i (for h2 = tanh(W2 @ h1 + b2)) and column i (for u = W2^T @ g2)
    float w2row[HID];
    float w2col[HID];
#pragma unroll
    for (int j = 0; j < HID; ++j) {
        w2row[j] = W2[i * HID + j];
        w2col[j] = W2[j * HID + i];
    }

    float q = x0[2 * b + 0];
    float p = x0[2 * b + 1];

    if (lane == 0) {
        out[2 * b + 0] = q;
        out[2 * b + 1] = p;
    }

    // dynamics: kq = dH/dp, kp = -dH/dq for the wave's (xq, xp)
    auto dynamics = [&](float xq, float xp, float& kq, float& kp) {
        const float pre1 = fmaf(w1a, xq, fmaf(w1b, xp, b1i));
        const float h1   = fast_tanh(pre1);

        // pre2[i] = b2[i] + sum_j W2[i,j] * h1[j]   (h1[j] broadcast via readlane)
        float a0 = b2i, a1 = 0.f, a2 = 0.f, a3 = 0.f;
#pragma unroll
        for (int j = 0; j < HID; j += 4) {
            a0 = fmaf(bcast_lane(h1, j + 0), w2row[j + 0], a0);
            a1 = fmaf(bcast_lane(h1, j + 1), w2row[j + 1], a1);
            a2 = fmaf(bcast_lane(h1, j + 2), w2row[j + 2], a2);
            a3 = fmaf(bcast_lane(h1, j + 3), w2row[j + 3], a3);
        }
        const float h2 = fast_tanh((a0 + a1) + (a2 + a3));
        const float g2 = w3i * fmaf(-h2, h2, 1.0f);

        // u[i] = sum_j g2[j] * W2[j,i]
        float c0 = 0.f, c1 = 0.f, c2 = 0.f, c3 = 0.f;
#pragma unroll
        for (int j = 0; j < HID; j += 4) {
            c0 = fmaf(bcast_lane(g2, j + 0), w2col[j + 0], c0);
            c1 = fmaf(bcast_lane(g2, j + 1), w2col[j + 1], c1);
            c2 = fmaf(bcast_lane(g2, j + 2), w2col[j + 2], c2);
            c3 = fmaf(bcast_lane(g2, j + 3), w2col[j + 3], c3);
        }
        const float u  = (c0 + c1) + (c2 + c3);
        const float g1 = u * fmaf(-h1, h1, 1.0f);

        // dHdx[d] = sum_i g1[i] * W1[i,d]  -> butterfly reduce across 64 lanes
        float s0 = g1 * w1a;
        float s1 = g1 * w1b;
#pragma unroll
        for (int m = 1; m < 64; m <<= 1) {
            s0 += __shfl_xor(s0, m, 64);
            s1 += __shfl_xor(s1, m, 64);
        }
        kq = s1;     //  dH/dp
        kp = -s0;    // -dH/dq
    };

#pragma unroll 1
    for (int s = 0; s < TSTEPS - 1; ++s) {
        float kq1, kp1, kq2, kp2, kq3, kp3, kq4, kp4;
        dynamics(q, p, kq1, kp1);
        dynamics(fmaf(hdt, kq1, q), fmaf(hdt, kp1, p), kq2, kp2);
        dynamics(fmaf(hdt, kq2, q), fmaf(hdt, kp2, p), kq3, kp3);
        dynamics(fmaf(dt,  kq3, q), fmaf(dt,  kp3, p), kq4, kp4);
        q = fmaf(sdt, kq1 + 2.f * kq2 + 2.f * kq3 + kq4, q);
        p = fmaf(sdt, kp1 + 2.f * kp2 + 2.f * kp3 + kp4, p);
        if (lane == 0) {
            out[(s + 1) * (BATCH * 2) + 2 * b + 0] = q;
            out[(s + 1) * (BATCH * 2) + 2 * b + 1] = p;
        }
    }
}

extern "C" void kernel_launch(void* const* d_in, const int* in_sizes, int n_in,
                              void* d_out, int out_size, void* d_ws, size_t ws_size,
                              hipStream_t stream) {
    const float* t  = (const float*)d_in[0];
    const float* x0 = (const float*)d_in[1];
    const float* W1 = (const float*)d_in[2];
    const float* b1 = (const float*)d_in[3];
    const float* W2 = (const float*)d_in[4];
    const float* b2 = (const float*)d_in[5];
    const float* W3 = (const float*)d_in[6];
    // d_in[7] = b3: additive constant in H, cancels in dH/dx — unused.

    // 2048 batch elements, one wave (64 lanes) each; 4 waves per 256-thread block
    hnn_rk4_kernel<<<dim3(BATCH / 4), dim3(256), 0, stream>>>(
        t, x0, W1, b1, W2, b2, W3, (float*)d_out);
}